// Round 1
// baseline (241.022 us; speedup 1.0000x reference)
//
#include <hip/hip_runtime.h>
#include <math.h>

constexpr int BDIM  = 256;
constexpr int Bsz   = 16, Asz = 3, Hsz = 80, Wsz = 80;
constexpr int Csz   = 84;                 // 4 + 80
constexpr int HWsz  = Hsz * Wsz;          // 6400
constexpr int BAsz  = Bsz * Asz;          // 48
constexpr int TOTAL = BAsz * HWsz;        // 307200
constexpr int NTGT  = 64;
constexpr int NCOMBO = BAsz * NTGT;       // 3072
constexpr int NBLK  = TOTAL / BDIM;       // 1200

__device__ __forceinline__ float softplus_f(float x) {
    // matches jax.nn.softplus = logaddexp(x, 0): stable for both signs
    return log1pf(expf(-fabsf(x))) + fmaxf(x, 0.f);
}

__global__ __launch_bounds__(BDIM)
void yolo_main(const float* __restrict__ pred,
               const float* __restrict__ targets,
               float* __restrict__ acc) {
    int tid = blockIdx.x * BDIM + threadIdx.x;

    float sp_all = 0.f, sp_tgt = 0.f, loc = 0.f, cls = 0.f, obj = 0.f;

    // --- no-obj path: one anchor-cell per thread, channel 4 only ---
    if (tid < TOTAL) {
        float p4 = pred[(size_t)tid * Csz + 4];
        sp_all = softplus_f(p4);
    }

    // --- target path: first 3072 threads, one (b,a,target) combo each ---
    if (tid < NCOMBO) {
        int t  = tid & (NTGT - 1);
        int ba = tid >> 6;                    // NTGT == 64
        float cid_f = targets[t * 5 + 0];
        float tx    = targets[t * 5 + 1];
        float ty    = targets[t * 5 + 2];
        float tw    = targets[t * 5 + 3];
        float th    = targets[t * 5 + 4];
        int gx = min(max((int)floorf(tx * (float)Wsz), 0), Wsz - 1);
        int gy = min(max((int)floorf(ty * (float)Hsz), 0), Hsz - 1);
        int cell = gy * Wsz + gx;
        const float* p = pred + ((size_t)ba * HWsz + cell) * Csz;

        // loc: channels 0..3 vs (tx,ty,tw,th)
        float d0 = p[0] - tx, d1 = p[1] - ty, d2 = p[2] - tw, d3 = p[3] - th;
        loc = d0 * d0 + d1 * d1 + d2 * d2 + d3 * d3;

        // cls: channels 4..83, softplus(x) - x*onehot
        int cid = (int)cid_f;
        float csum = 0.f;
        #pragma unroll 4
        for (int c = 0; c < 80; ++c) {
            csum += softplus_f(p[4 + c]);
        }
        csum -= p[4 + cid];
        cls = csum;

        float p4 = p[4];
        obj    = softplus_f(-p4);
        sp_tgt = softplus_f(p4);   // subtracted from no-obj sum
    }

    // --- block reduction of 5 accumulators ---
    float vals[5] = {sp_all, sp_tgt, loc, cls, obj};
    #pragma unroll
    for (int k = 0; k < 5; ++k) {
        float v = vals[k];
        #pragma unroll
        for (int o = 32; o > 0; o >>= 1) v += __shfl_down(v, o, 64);
        vals[k] = v;
    }
    __shared__ float sm[4][5];
    int lane = threadIdx.x & 63, wid = threadIdx.x >> 6;
    if (lane == 0) {
        #pragma unroll
        for (int k = 0; k < 5; ++k) sm[wid][k] = vals[k];
    }
    __syncthreads();
    if (threadIdx.x == 0) {
        #pragma unroll
        for (int k = 0; k < 5; ++k) {
            float s = sm[0][k] + sm[1][k] + sm[2][k] + sm[3][k];
            atomicAdd(&acc[k], s);
        }
    }
}

__global__ void yolo_final(const float* __restrict__ acc, float* __restrict__ out) {
    float sp_all = acc[0], sp_tgt = acc[1], loc = acc[2], cls = acc[3], obj = acc[4];
    float loc_loss = loc / (float)(NCOMBO * 4);                 // 12288
    float cls_loss = cls / (float)(NCOMBO * 80);                // 245760
    float obj_loss = obj / (float)NCOMBO;                       // 3072
    float noobj    = (sp_all - sp_tgt) / (float)(BAsz * (HWsz - NTGT)); // 304128
    out[0] = loc_loss + cls_loss + obj_loss + 0.5f * noobj;
}

extern "C" void kernel_launch(void* const* d_in, const int* in_sizes, int n_in,
                              void* d_out, int out_size, void* d_ws, size_t ws_size,
                              hipStream_t stream) {
    const float* pred    = (const float*)d_in[0];
    const float* targets = (const float*)d_in[1];
    float* acc = (float*)d_ws;           // 5 floats of scratch
    float* out = (float*)d_out;

    hipMemsetAsync(acc, 0, 5 * sizeof(float), stream);
    yolo_main<<<NBLK, BDIM, 0, stream>>>(pred, targets, acc);
    yolo_final<<<1, 1, 0, stream>>>(acc, out);
}